// Round 8
// baseline (266.921 us; speedup 1.0000x reference)
//
#include <hip/hip_runtime.h>
#include <hip/hip_bf16.h>
#include <math.h>

constexpr int BB = 2;
constexpr int LL = 1024;
constexpr int DD = 768;
constexpr int HH = 12;
constexpr int NEz = 42;
constexpr int MM = 8;
constexpr int NPp = 1722;
constexpr int CC = 97;
constexpr int FF = 256;
constexpr int PAIRS = NEz * NEz;         // 1764
constexpr int TOTAL = BB * NPp;          // 3444
constexpr int MT = 64;                   // rows per k_bil tile
constexpr int NT = 54;                   // tiles (padded 3456)
constexpr int PADR = 3456;
constexpr int NOG = 36;                  // o-groups
constexpr int GRID = NT * 2 * NOG;       // 3888 = 8*486

typedef float f32x4 __attribute__((ext_vector_type(4)));
typedef short bf16x8 __attribute__((ext_vector_type(8)));
typedef unsigned int u32x2 __attribute__((ext_vector_type(2)));

__device__ inline short f2bs(float x) {
    __hip_bfloat16 b = __float2bfloat16(x);
    return *(short*)&b;
}

// ---------------- K2: ent_emb = masked logsumexp over M mentions ----------------
__global__ void k_ent_emb(const float* __restrict__ seq, const int* __restrict__ midx,
                          const int* __restrict__ mmask, float* __restrict__ ent_emb) {
    int be = blockIdx.x;
    int b = be / NEz;
    int tid = threadIdx.x;
    int idx[MM], msk[MM];
#pragma unroll
    for (int m = 0; m < MM; ++m) {
        idx[m] = midx[be * MM + m];
        msk[m] = mmask[be * MM + m];
    }
    const float* sb = seq + (size_t)b * LL * DD;
    for (int d = tid; d < DD; d += 256) {
        float v[MM];
        float mx = -1e30f;
#pragma unroll
        for (int m = 0; m < MM; ++m) {
            v[m] = msk[m] ? sb[(size_t)idx[m] * DD + d] : -1e30f;
            mx = fmaxf(mx, v[m]);
        }
        float s = 0.f;
#pragma unroll
        for (int m = 0; m < MM; ++m) s += expf(v[m] - mx);
        ent_emb[(size_t)be * DD + d] = mx + logf(s);
    }
}

// ---------------- K3: ent_att ----------------
__global__ void k_ent_att(const float* __restrict__ att, const int* __restrict__ midx,
                          const int* __restrict__ mmask, float* __restrict__ ea) {
    int beh = blockIdx.x;
    int h = beh % HH;
    int be = beh / HH;
    int b = be / NEz;
    int tid = threadIdx.x;
    int idx[MM], msk[MM];
    float msum = 0.f;
#pragma unroll
    for (int m = 0; m < MM; ++m) {
        idx[m] = midx[be * MM + m];
        msk[m] = mmask[be * MM + m];
        msum += (float)msk[m];
    }
    float inv = 1.f / msum;
    const float* ab = att + ((size_t)b * HH + h) * LL * LL;
#pragma unroll
    for (int li = 0; li < 4; ++li) {
        int l = tid + li * 256;
        float acc = 0.f;
#pragma unroll
        for (int m = 0; m < MM; ++m)
            if (msk[m]) acc += ab[(size_t)idx[m] * LL + l];
        ea[(size_t)beh * LL + l] = acc * inv;
    }
}

// ---------------- K4a: per (b, l-chunk of 8): ht partial sums + projections ------
__global__ void k_pairAB(const float* __restrict__ ea, const float* __restrict__ seq,
                         const float* __restrict__ Wl, float* __restrict__ szp) {
    int lcb = blockIdx.x;   // 0..127
    int b = blockIdx.y;
    int l0 = lcb * 8;
    int tid = threadIdx.x;  // 384 = 6 waves
    int lane = tid & 63;
    int e1 = (tid >> 6) * 8 + (lane >> 3);
    int l = lane & 7;

    __shared__ float S[NEz][HH][9];
    __shared__ float sw[8][3];
    __shared__ float swp[24][17];

    for (int idx = tid; idx < NEz * HH * 8; idx += 384) {
        int e = idx / 96, rem = idx % 96;
        int h = rem / 8, ll = rem % 8;
        S[e][h][ll] = ea[((size_t)(b * NEz + e) * HH + h) * LL + l0 + ll];
    }
    {
        int cpair = tid % 24, s = tid / 24;
        if (s < 16) {
            int ll = cpair / 3, kk = cpair % 3;
            const float* sr = seq + ((size_t)b * LL + l0 + ll) * DD;
            float p = 0.f;
            for (int d = s * 48; d < s * 48 + 48; ++d) p += sr[d] * Wl[d * 3 + kk];
            swp[cpair][s] = p;
        }
    }
    __syncthreads();
    if (tid < 24) {
        float s = 0.f;
#pragma unroll
        for (int i = 0; i < 16; ++i) s += swp[tid][i];
        sw[tid / 3][tid % 3] = s;
    }
    __syncthreads();

    bool act = e1 < NEz;
    float e1r[HH];
#pragma unroll
    for (int h = 0; h < HH; ++h) e1r[h] = act ? S[e1][h][l] : 0.f;
    float sw0 = sw[l][0], sw1 = sw[l][1], sw2 = sw[l][2];

    for (int e2 = 0; e2 < NEz; ++e2) {
        float ht = 0.f;
#pragma unroll
        for (int h = 0; h < HH; ++h) ht += e1r[h] * S[e2][h][l];
        ht *= (1.0f / HH);
        float v0 = ht, v1 = ht * sw0, v2 = ht * sw1, v3 = ht * sw2;
#pragma unroll
        for (int off = 1; off < 8; off <<= 1) {
            v0 += __shfl_xor(v0, off);
            v1 += __shfl_xor(v1, off);
            v2 += __shfl_xor(v2, off);
            v3 += __shfl_xor(v3, off);
        }
        if (act && l == 0) {
            float4 o4 = make_float4(v0, v1, v2, v3);
            *(float4*)&szp[(((size_t)(b * PAIRS + e1 * NEz + e2)) * 128 + lcb) * 4] = o4;
        }
    }
}

// ---------------- K4b: reduce partials -> zz (8 threads per pair) ----------------
__global__ void k_zz(const float* __restrict__ szp, const float* __restrict__ blin,
                     float* __restrict__ zz) {
    int idx = blockIdx.x * 256 + threadIdx.x;
    int bp = idx >> 3, s8 = idx & 7;
    if (bp >= BB * PAIRS) return;
    const float4* s = (const float4*)(szp + (size_t)bp * 512) + s8 * 16;
    float v0 = 0.f, v1 = 0.f, v2 = 0.f, v3 = 0.f;
#pragma unroll
    for (int i = 0; i < 16; ++i) {
        float4 a = s[i];
        v0 += a.x; v1 += a.y; v2 += a.z; v3 += a.w;
    }
#pragma unroll
    for (int off = 1; off < 8; off <<= 1) {
        v0 += __shfl_xor(v0, off);
        v1 += __shfl_xor(v1, off);
        v2 += __shfl_xor(v2, off);
        v3 += __shfl_xor(v3, off);
    }
    if (s8 == 0) {
        float inv = 1.f / (v0 + 1e-5f);
        float4 o4 = make_float4(v1 * inv + blin[0], v2 * inv + blin[1], v3 * inv + blin[2], 0.f);
        *(float4*)&zz[(size_t)bp * 4] = o4;
    }
}

// ---------------- K5: EWh/EWt = ent_emb @ W_head/tail + bias (column-tiled) ------
__global__ void k_ew(const float* __restrict__ ent_emb, const float* __restrict__ Wh,
                     const float* __restrict__ bh, const float* __restrict__ Wt,
                     const float* __restrict__ bt, float* __restrict__ EWh,
                     float* __restrict__ EWt) {
    int cb = blockIdx.x;            // 64 blocks x 8 cols (of 512 = head|tail)
    int tid = threadIdx.x;          // 256
    int colg = cb * 8 + (tid & 7);
    int rg = tid >> 3;              // 0..31
    bool head = colg < FF;
    int col = head ? colg : colg - FF;
    const float* W = head ? Wh : Wt;
    float bias = head ? bh[col] : bt[col];
    float* dst = head ? EWh : EWt;
    for (int r = rg; r < BB * NEz; r += 32) {
        float s = bias;
        const float* e = ent_emb + (size_t)r * DD;
        for (int d = 0; d < DD; ++d) s += e[d] * W[(size_t)d * FF + col];
        dst[(size_t)r * FF + col] = s;
    }
}

// ---------------- K6a: Wf = fragment-ordered bf16 image of W_bil -----------------
// slot ((((o*2+kr)*4+kc)*16 + wc*4+ni)*64 + lane) holds bf16x8 of
//   W[o][kr*128 + kc*32 + (lane>>4)*8 + j][wc*64 + ni*16 + (lane&15)]
__global__ void k_wt(const float* __restrict__ Wb, short* __restrict__ Wf) {
    int o = blockIdx.x >> 1, kr = blockIdx.x & 1;
    int tid = threadIdx.x;          // 256
    __shared__ float T[32][257];
    bf16x8* Wf8 = (bf16x8*)Wf;
    for (int kc = 0; kc < 4; ++kc) {
        __syncthreads();
        const float* src = Wb + (size_t)o * FF * FF + (size_t)(kr * 128 + kc * 32) * FF;
#pragma unroll
        for (int i = 0; i < 32; ++i) {
            int flat = i * 256 + tid;
            T[flat >> 8][flat & 255] = src[flat];
        }
        __syncthreads();
#pragma unroll
        for (int it = 0; it < 4; ++it) {
            int slot = it * 256 + tid;          // 0..1023
            int l = slot & 63, wi = slot >> 6;  // wi 0..15
            int kl = (l >> 4) * 8;
            int c = (wi >> 2) * 64 + (wi & 3) * 16 + (l & 15);
            bf16x8 v;
#pragma unroll
            for (int j = 0; j < 8; ++j) v[j] = f2bs(T[kl + j][c]);
            Wf8[((((size_t)o * 2 + kr) * 4 + kc) * 16 + wi) * 64 + l] = v;
        }
    }
}

// ---------------- K6b: HSf (A-fragment images) + TSt (transposed) ----------------
__global__ void k_prep(const float* __restrict__ EWh, const float* __restrict__ EWt,
                       const float* __restrict__ zz, const float* __restrict__ Wseg,
                       const float* __restrict__ bseg, const int* __restrict__ hts,
                       short* __restrict__ HSf, unsigned short* __restrict__ TSt) {
    int mt = blockIdx.x;            // 54
    int tid = threadIdx.x;          // 256
    int p0 = mt * MT;

    __shared__ float Hs[64][257];
    __shared__ float Ts[64][257];
    __shared__ float wsg[4][256];
    __shared__ float zr[64][3];
    __shared__ int offh[64], offt[64];

    if (tid < 64) {
        int p = p0 + tid;
        if (p < TOTAL) {
            int b = p / NPp;
            int e1 = hts[p * 2], e2 = hts[p * 2 + 1];
            offh[tid] = (b * NEz + e1) * FF;
            offt[tid] = (b * NEz + e2) * FF;
            float4 z4 = *(const float4*)(zz + (size_t)(b * PAIRS + e1 * NEz + e2) * 4);
            zr[tid][0] = z4.x; zr[tid][1] = z4.y; zr[tid][2] = z4.z;
        } else {
            offh[tid] = -1; offt[tid] = -1;
            zr[tid][0] = zr[tid][1] = zr[tid][2] = 0.f;
        }
    }
    wsg[0][tid] = Wseg[tid];
    wsg[1][tid] = Wseg[FF + tid];
    wsg[2][tid] = Wseg[2 * FF + tid];
    wsg[3][tid] = bseg[tid];
    __syncthreads();

    {
        int r = tid >> 2, cq = tid & 3;
        int oh = offh[r], ot = offt[r];
        float z0 = zr[r][0], z1 = zr[r][1], z2 = zr[r][2];
#pragma unroll 4
        for (int j = 0; j < 64; ++j) {
            int c = cq * 64 + j;
            float ht = fmaxf(z0 * wsg[0][c] + z1 * wsg[1][c] + z2 * wsg[2][c] + wsg[3][c], 0.f);
            float hv = 0.f, tv = 0.f;
            if (oh >= 0) {
                hv = tanhf(EWh[oh + c] + ht);
                tv = tanhf(EWt[ot + c] + ht);
            }
            Hs[r][c] = hv;
            Ts[r][c] = tv;
        }
    }
    __syncthreads();

    // A fragments: slot ((mt*2+kr)*16 + mi*4+kc)*64 + lane
    bf16x8* HSf8 = (bf16x8*)HSf;
#pragma unroll
    for (int it = 0; it < 8; ++it) {
        int slot = it * 256 + tid;          // 0..2047
        int l = slot & 63, fidx = slot >> 6;
        int krr = fidx >> 4, mi = (fidx >> 2) & 3, kc = fidx & 3;
        int r = mi * 16 + (l & 15);
        int k = krr * 128 + kc * 32 + (l >> 4) * 8;
        bf16x8 v;
#pragma unroll
        for (int j = 0; j < 8; ++j) v[j] = f2bs(Hs[r][k + j]);
        HSf8[((size_t)(mt * 2 + krr) * 16 + (mi * 4 + kc)) * 64 + l] = v;
    }
    // TSt[c][PADR]
    {
        int r = tid & 63, cg = tid >> 6;
        for (int cc = 0; cc < 64; ++cc) {
            int c = cg * 64 + cc;
            TSt[(size_t)c * PADR + p0 + r] = (unsigned short)f2bs(Ts[r][c]);
        }
    }
}

// ---------------- K6c: bilinear, barrier-free reg-resident MFMA ------------------
// 256 thr = 4 waves (wc 0..3).  Per block: M=64 x N=256 x K=128 (kr-split),
// A + TS in VGPRs (loaded once), B streamed global->reg depth-2.  No LDS staging,
// no barriers in the k-loop.  kr partials combined via 2-addend atomicAdd.
#define LDB(DST, O_, KC_) do { \
    const bf16x8* bp_ = Wb8 + ((((size_t)(O_) * 2 + kr) * 4 + (KC_)) * 16 + wc * 4) * 64 + lane; \
    DST[0] = bp_[0]; DST[1] = bp_[64]; DST[2] = bp_[128]; DST[3] = bp_[192]; \
} while (0)

#define PHASE(KC_, BSRC) do { \
    __builtin_amdgcn_s_setprio(1); \
    _Pragma("unroll") \
    for (int mi_ = 0; mi_ < 4; ++mi_) \
        _Pragma("unroll") \
        for (int ni_ = 0; ni_ < 4; ++ni_) \
            acc[mi_][ni_] = __builtin_amdgcn_mfma_f32_16x16x32_bf16(af[mi_ * 4 + (KC_)], BSRC[ni_], acc[mi_][ni_], 0, 0, 0); \
    __builtin_amdgcn_s_setprio(0); \
} while (0)

#define SYNC_RED() do { \
    asm volatile("s_waitcnt lgkmcnt(0)" ::: "memory"); \
    __builtin_amdgcn_sched_barrier(0); \
    __builtin_amdgcn_s_barrier(); \
    __builtin_amdgcn_sched_barrier(0); \
} while (0)

__launch_bounds__(256, 2)
__global__ void k_bil(const short* __restrict__ HSf, const unsigned short* __restrict__ TSt,
                      const short* __restrict__ Wf, const float* __restrict__ bbil,
                      float* __restrict__ out) {
    int f = blockIdx.x;
    int wg = (f & 7) * 486 + (f >> 3);   // bijective XCD-chunked
    int g = wg / 108;
    int rem = wg % 108;
    int mt = rem >> 1, kr = rem & 1;
    int og = (g & 1) ? (35 - (g >> 1)) : (g >> 1);   // pair big/small o-groups per XCD
    int p0 = mt * MT;
    int nO = (og < 25) ? 3 : 2;

    int tid = threadIdx.x;
    int lane = tid & 63, wc = tid >> 6;
    int lr = lane & 15, lg = lane >> 4;

    __shared__ float red[64][4];

    const bf16x8* Wb8 = (const bf16x8*)Wf;

    // A fragments in registers (64 VGPR), loaded once
    bf16x8 af[16];
    {
        const bf16x8* Ab = (const bf16x8*)HSf + ((size_t)(mt * 2 + kr) * 16) * 64 + lane;
#pragma unroll
        for (int i = 0; i < 16; ++i) af[i] = Ab[i * 64];
    }
    // TS fragments in registers (32 VGPR), o-independent
    u32x2 tsv[4][4];
#pragma unroll
    for (int mi = 0; mi < 4; ++mi)
#pragma unroll
        for (int ni = 0; ni < 4; ++ni)
            tsv[mi][ni] = *(const u32x2*)(TSt + (size_t)(wc * 64 + ni * 16 + lr) * PADR +
                                          p0 + mi * 16 + lg * 4);

    bf16x8 b0[4], b1[4];
    LDB(b0, og, 0);
    LDB(b1, og, 1);

    for (int oi = 0; oi < nO; ++oi) {
        int o = og + 36 * oi;
        int on = (oi + 1 < nO) ? (o + 36) : o;

        f32x4 acc[4][4];
#pragma unroll
        for (int mi = 0; mi < 4; ++mi)
#pragma unroll
            for (int ni = 0; ni < 4; ++ni) acc[mi][ni] = (f32x4){0.f, 0.f, 0.f, 0.f};

        PHASE(0, b0);  LDB(b0, o, 2);
        PHASE(1, b1);  LDB(b1, o, 3);
        PHASE(2, b0);  LDB(b0, on, 0);
        PHASE(3, b1);  LDB(b1, on, 1);

        // epilogue: dot with TS, reduce over the 16 lr lanes, cross-wave via red
#pragma unroll
        for (int mi = 0; mi < 4; ++mi) {
            float s0 = 0.f, s1 = 0.f, s2 = 0.f, s3 = 0.f;
#pragma unroll
            for (int ni = 0; ni < 4; ++ni) {
                unsigned lo = tsv[mi][ni][0], hi = tsv[mi][ni][1];
                s0 += acc[mi][ni][0] * __uint_as_float(lo << 16);
                s1 += acc[mi][ni][1] * __uint_as_float(lo & 0xFFFF0000u);
                s2 += acc[mi][ni][2] * __uint_as_float(hi << 16);
                s3 += acc[mi][ni][3] * __uint_as_float(hi & 0xFFFF0000u);
            }
#pragma unroll
            for (int off = 1; off < 16; off <<= 1) {
                s0 += __shfl_xor(s0, off);
                s1 += __shfl_xor(s1, off);
                s2 += __shfl_xor(s2, off);
                s3 += __shfl_xor(s3, off);
            }
            if (lr == 0) {
                int rb = mi * 16 + lg * 4;
                red[rb + 0][wc] = s0;
                red[rb + 1][wc] = s1;
                red[rb + 2][wc] = s2;
                red[rb + 3][wc] = s3;
            }
        }
        SYNC_RED();
        if (lane < 16) {
            int row = wc * 16 + lane;
            int p = p0 + row;
            if (p < TOTAL) {
                float v = red[row][0] + red[row][1] + red[row][2] + red[row][3] +
                          0.5f * bbil[o];
                atomicAdd(out + (size_t)p * CC + o, v);
            }
        }
        SYNC_RED();
    }
}
#undef LDB
#undef PHASE
#undef SYNC_RED

extern "C" void kernel_launch(void* const* d_in, const int* in_sizes, int n_in,
                              void* d_out, int out_size, void* d_ws, size_t ws_size,
                              hipStream_t stream) {
    const float* seq   = (const float*)d_in[0];
    const float* att   = (const float*)d_in[1];
    const int*   midx  = (const int*)d_in[2];
    const int*   mmask = (const int*)d_in[3];
    const int*   hts   = (const int*)d_in[4];
    const float* Wlin  = (const float*)d_in[5];
    const float* blin  = (const float*)d_in[6];
    const float* Wseg  = (const float*)d_in[7];
    const float* bseg  = (const float*)d_in[8];
    const float* Whead = (const float*)d_in[9];
    const float* bhead = (const float*)d_in[10];
    const float* Wtail = (const float*)d_in[11];
    const float* btail = (const float*)d_in[12];
    const float* Wbil  = (const float*)d_in[13];
    const float* bbil  = (const float*)d_in[14];
    float* out = (float*)d_out;

    float* ws = (float*)d_ws;
    float* ent_emb = ws;                                     // 64512 f
    float* ea      = ent_emb + BB * NEz * DD;                // 1032192 f
    float* szp     = ea + (size_t)BB * NEz * HH * LL;        // 1806336 f
    float* zz      = szp + (size_t)BB * PAIRS * 128 * 4;     // 14112 f
    float* EWh     = zz + (size_t)BB * PAIRS * 4;            // 21504 f
    float* EWt     = EWh + BB * NEz * FF;                    // 21504 f
    short* Wf      = (short*)(EWt + BB * NEz * FF);          // 97*2*4*16*64*8 sh = 12.7 MB
    short* HSf     = Wf + (size_t)CC * 2 * 4 * 16 * 64 * 8;  // 54*2*16*64*8 sh
    unsigned short* TSt = (unsigned short*)(HSf + (size_t)NT * 2 * 16 * 64 * 8);  // 256*3456

    hipMemsetAsync(out, 0, (size_t)out_size * sizeof(float), stream);
    k_ent_emb<<<BB * NEz, 256, 0, stream>>>(seq, midx, mmask, ent_emb);
    k_ent_att<<<BB * NEz * HH, 256, 0, stream>>>(att, midx, mmask, ea);
    k_pairAB<<<dim3(128, BB), 384, 0, stream>>>(ea, seq, Wlin, szp);
    k_zz<<<(BB * PAIRS * 8 + 255) / 256, 256, 0, stream>>>(szp, blin, zz);
    k_ew<<<64, 256, 0, stream>>>(ent_emb, Whead, bhead, Wtail, btail, EWh, EWt);
    k_wt<<<CC * 2, 256, 0, stream>>>(Wbil, Wf);
    k_prep<<<NT, 256, 0, stream>>>(EWh, EWt, zz, Wseg, bseg, hts, HSf, TSt);
    k_bil<<<GRID, 256, 0, stream>>>(HSf, TSt, Wf, bbil, out);
}

// Round 9
// 199.024 us; speedup vs baseline: 1.3412x; 1.3412x over previous
//
#include <hip/hip_runtime.h>
#include <hip/hip_bf16.h>
#include <math.h>

constexpr int BB = 2;
constexpr int LL = 1024;
constexpr int DD = 768;
constexpr int HH = 12;
constexpr int NEz = 42;
constexpr int MM = 8;
constexpr int NPp = 1722;
constexpr int CC = 97;
constexpr int FF = 256;
constexpr int PAIRS = NEz * NEz;         // 1764
constexpr int TOTAL = BB * NPp;          // 3444
constexpr int MTv = 128;                 // rows per k_bil tile
constexpr int NTt = 28;                  // tiles (padded 3584)
constexpr int PADR = 3584;
constexpr int NOGv = 36;                 // o-groups
constexpr int NWGv = 1008;               // 8 XCD-slots * 126

typedef float f32x4 __attribute__((ext_vector_type(4)));
typedef short bf16x8 __attribute__((ext_vector_type(8)));
typedef unsigned int u32x2 __attribute__((ext_vector_type(2)));

__device__ inline short f2bs(float x) {
    __hip_bfloat16 b = __float2bfloat16(x);
    return *(short*)&b;
}
__device__ inline void gload16(const void* g, void* l) {
    __builtin_amdgcn_global_load_lds((const __attribute__((address_space(1))) unsigned int*)g,
                                     (__attribute__((address_space(3))) unsigned int*)l, 16, 0, 0);
}

// ---------------- K2: ent_emb = masked logsumexp over M mentions ----------------
__global__ void k_ent_emb(const float* __restrict__ seq, const int* __restrict__ midx,
                          const int* __restrict__ mmask, float* __restrict__ ent_emb) {
    int be = blockIdx.x;
    int b = be / NEz;
    int tid = threadIdx.x;
    int idx[MM], msk[MM];
#pragma unroll
    for (int m = 0; m < MM; ++m) {
        idx[m] = midx[be * MM + m];
        msk[m] = mmask[be * MM + m];
    }
    const float* sb = seq + (size_t)b * LL * DD;
    for (int d = tid; d < DD; d += 256) {
        float v[MM];
        float mx = -1e30f;
#pragma unroll
        for (int m = 0; m < MM; ++m) {
            v[m] = msk[m] ? sb[(size_t)idx[m] * DD + d] : -1e30f;
            mx = fmaxf(mx, v[m]);
        }
        float s = 0.f;
#pragma unroll
        for (int m = 0; m < MM; ++m) s += expf(v[m] - mx);
        ent_emb[(size_t)be * DD + d] = mx + logf(s);
    }
}

// ---------------- K3: ent_att ----------------
__global__ void k_ent_att(const float* __restrict__ att, const int* __restrict__ midx,
                          const int* __restrict__ mmask, float* __restrict__ ea) {
    int beh = blockIdx.x;
    int h = beh % HH;
    int be = beh / HH;
    int b = be / NEz;
    int tid = threadIdx.x;
    int idx[MM], msk[MM];
    float msum = 0.f;
#pragma unroll
    for (int m = 0; m < MM; ++m) {
        idx[m] = midx[be * MM + m];
        msk[m] = mmask[be * MM + m];
        msum += (float)msk[m];
    }
    float inv = 1.f / msum;
    const float* ab = att + ((size_t)b * HH + h) * LL * LL;
#pragma unroll
    for (int li = 0; li < 4; ++li) {
        int l = tid + li * 256;
        float acc = 0.f;
#pragma unroll
        for (int m = 0; m < MM; ++m)
            if (msk[m]) acc += ab[(size_t)idx[m] * LL + l];
        ea[(size_t)beh * LL + l] = acc * inv;
    }
}

// ---------------- K4a: per (b, l-chunk of 8): ht partial sums + projections ------
__global__ void k_pairAB(const float* __restrict__ ea, const float* __restrict__ seq,
                         const float* __restrict__ Wl, float* __restrict__ szp) {
    int lcb = blockIdx.x;   // 0..127
    int b = blockIdx.y;
    int l0 = lcb * 8;
    int tid = threadIdx.x;  // 384 = 6 waves
    int lane = tid & 63;
    int e1 = (tid >> 6) * 8 + (lane >> 3);
    int l = lane & 7;

    __shared__ float S[NEz][HH][9];
    __shared__ float sw[8][3];
    __shared__ float swp[24][17];

    for (int idx = tid; idx < NEz * HH * 8; idx += 384) {
        int e = idx / 96, rem = idx % 96;
        int h = rem / 8, ll = rem % 8;
        S[e][h][ll] = ea[((size_t)(b * NEz + e) * HH + h) * LL + l0 + ll];
    }
    {
        int cpair = tid % 24, s = tid / 24;
        if (s < 16) {
            int ll = cpair / 3, kk = cpair % 3;
            const float* sr = seq + ((size_t)b * LL + l0 + ll) * DD;
            float p = 0.f;
            for (int d = s * 48; d < s * 48 + 48; ++d) p += sr[d] * Wl[d * 3 + kk];
            swp[cpair][s] = p;
        }
    }
    __syncthreads();
    if (tid < 24) {
        float s = 0.f;
#pragma unroll
        for (int i = 0; i < 16; ++i) s += swp[tid][i];
        sw[tid / 3][tid % 3] = s;
    }
    __syncthreads();

    bool act = e1 < NEz;
    float e1r[HH];
#pragma unroll
    for (int h = 0; h < HH; ++h) e1r[h] = act ? S[e1][h][l] : 0.f;
    float sw0 = sw[l][0], sw1 = sw[l][1], sw2 = sw[l][2];

    for (int e2 = 0; e2 < NEz; ++e2) {
        float ht = 0.f;
#pragma unroll
        for (int h = 0; h < HH; ++h) ht += e1r[h] * S[e2][h][l];
        ht *= (1.0f / HH);
        float v0 = ht, v1 = ht * sw0, v2 = ht * sw1, v3 = ht * sw2;
#pragma unroll
        for (int off = 1; off < 8; off <<= 1) {
            v0 += __shfl_xor(v0, off);
            v1 += __shfl_xor(v1, off);
            v2 += __shfl_xor(v2, off);
            v3 += __shfl_xor(v3, off);
        }
        if (act && l == 0) {
            float4 o4 = make_float4(v0, v1, v2, v3);
            *(float4*)&szp[(((size_t)(b * PAIRS + e1 * NEz + e2)) * 128 + lcb) * 4] = o4;
        }
    }
}

// ---------------- K4b: reduce partials -> zz (8 threads per pair) ----------------
__global__ void k_zz(const float* __restrict__ szp, const float* __restrict__ blin,
                     float* __restrict__ zz) {
    int idx = blockIdx.x * 256 + threadIdx.x;
    int bp = idx >> 3, s8 = idx & 7;
    if (bp >= BB * PAIRS) return;
    const float4* s = (const float4*)(szp + (size_t)bp * 512) + s8 * 16;
    float v0 = 0.f, v1 = 0.f, v2 = 0.f, v3 = 0.f;
#pragma unroll
    for (int i = 0; i < 16; ++i) {
        float4 a = s[i];
        v0 += a.x; v1 += a.y; v2 += a.z; v3 += a.w;
    }
#pragma unroll
    for (int off = 1; off < 8; off <<= 1) {
        v0 += __shfl_xor(v0, off);
        v1 += __shfl_xor(v1, off);
        v2 += __shfl_xor(v2, off);
        v3 += __shfl_xor(v3, off);
    }
    if (s8 == 0) {
        float inv = 1.f / (v0 + 1e-5f);
        float4 o4 = make_float4(v1 * inv + blin[0], v2 * inv + blin[1], v3 * inv + blin[2], 0.f);
        *(float4*)&zz[(size_t)bp * 4] = o4;
    }
}

// ---------------- K5: EWh/EWt = ent_emb @ W_head/tail + bias (r2 style) ----------
__global__ void k_ew(const float* __restrict__ ent_emb, const float* __restrict__ Wh,
                     const float* __restrict__ bh, const float* __restrict__ Wt,
                     const float* __restrict__ bt, float* __restrict__ EWh,
                     float* __restrict__ EWt) {
    int be = blockIdx.x;
    int tid = threadIdx.x;          // 256
    __shared__ float e[DD];
    for (int d = tid; d < DD; d += 256) e[d] = ent_emb[(size_t)be * DD + d];
    __syncthreads();
    float ah = bh[tid], at = bt[tid];
    for (int d = 0; d < DD; ++d) {
        float ev = e[d];
        ah += ev * Wh[(size_t)d * FF + tid];
        at += ev * Wt[(size_t)d * FF + tid];
    }
    EWh[(size_t)be * FF + tid] = ah;
    EWt[(size_t)be * FF + tid] = at;
}

// ---------------- K6a: Wf = pre-swizzled 32KB LDS images of W_bil ----------------
// image (o, kc): byte (c*128 + k16*16) ^ ((c&7)<<4) = bf16x8 of W[o][kc*64+k16*8..+8][c]
__global__ void k_wt(const float* __restrict__ Wb, char* __restrict__ Wf) {
    int o = blockIdx.x >> 2, kc = blockIdx.x & 3;
    int tid = threadIdx.x;          // 256
    __shared__ float t64[64][257];
    const float* src = Wb + (size_t)o * FF * FF + (size_t)(kc * 64) * FF;
#pragma unroll
    for (int i = 0; i < 64; ++i) {
        int flat = i * 256 + tid;
        t64[flat >> 8][flat & 255] = src[flat];
    }
    __syncthreads();
    char* dst = Wf + ((size_t)o * 4 + kc) * 32768;
#pragma unroll
    for (int i = 0; i < 8; ++i) {
        int u = i * 256 + tid;
        int c = u >> 3, k16 = u & 7;
        bf16x8 v;
#pragma unroll
        for (int j = 0; j < 8; ++j) v[j] = f2bs(t64[k16 * 8 + j][c]);
        *(bf16x8*)(dst + ((c * 128 + k16 * 16) ^ ((c & 7) << 4))) = v;
    }
}

// ---------------- K6b: HSf (pre-swizzled 64KB A images, 128 rows) + TSt ----------
__global__ void k_prep(const float* __restrict__ EWh, const float* __restrict__ EWt,
                       const float* __restrict__ zz, const float* __restrict__ Wseg,
                       const float* __restrict__ bseg, const int* __restrict__ hts,
                       char* __restrict__ HSf, unsigned short* __restrict__ TSt) {
    int tile = blockIdx.x >> 1, half = blockIdx.x & 1;
    int tid = threadIdx.x;          // 256
    int p0 = tile * MTv;

    __shared__ int offh[128];
    __shared__ float zr[128][3];
    __shared__ float wsg[4][128];
    __shared__ float Et[128][133];

    if (tid < 128) {
        int p = p0 + tid;
        if (p < TOTAL) {
            int b = p / NPp;
            int e1 = hts[p * 2], e2 = hts[p * 2 + 1];
            offh[tid] = (b * NEz + e1) * FF;
            float4 z4 = *(const float4*)(zz + (size_t)(b * PAIRS + e1 * NEz + e2) * 4);
            zr[tid][0] = z4.x; zr[tid][1] = z4.y; zr[tid][2] = z4.z;
        } else {
            offh[tid] = -1;
            zr[tid][0] = zr[tid][1] = zr[tid][2] = 0.f;
        }
        int c = half * 128 + tid;
        wsg[0][tid] = Wseg[c];
        wsg[1][tid] = Wseg[FF + c];
        wsg[2][tid] = Wseg[2 * FF + c];
        wsg[3][tid] = bseg[c];
    }
    // stage EWt columns (coalesced rows -> LDS)
    {
        int r2 = tid >> 1, hc = tid & 1;
        int p = p0 + r2;
        int ot = -1;
        if (p < TOTAL) {
            int b = p / NPp;
            int e2 = hts[p * 2 + 1];
            ot = (b * NEz + e2) * FF;
        }
#pragma unroll
        for (int j = 0; j < 64; j += 4) {
            float4 v = make_float4(0.f, 0.f, 0.f, 0.f);
            if (ot >= 0) v = *(const float4*)(EWt + ot + half * 128 + hc * 64 + j);
            int cl = hc * 64 + j;
            Et[r2][cl] = v.x; Et[r2][cl + 1] = v.y; Et[r2][cl + 2] = v.z; Et[r2][cl + 3] = v.w;
        }
    }
    __syncthreads();

    // HS image half: bytes (r*512 + half*256 + k16*16) ^ ((r&7)<<4)
    char* dst = HSf + (size_t)tile * 65536;
#pragma unroll
    for (int i = 0; i < 8; ++i) {
        int u = i * 256 + tid;
        int r = u >> 4, k16 = u & 15;
        int oh = offh[r];
        bf16x8 v = {0, 0, 0, 0, 0, 0, 0, 0};
        if (oh >= 0) {
#pragma unroll
            for (int j = 0; j < 8; ++j) {
                int cl = k16 * 8 + j;
                float ht = fmaxf(zr[r][0] * wsg[0][cl] + zr[r][1] * wsg[1][cl] +
                                 zr[r][2] * wsg[2][cl] + wsg[3][cl], 0.f);
                v[j] = f2bs(tanhf(EWh[oh + half * 128 + cl] + ht));
            }
        }
        int byte = (r * 512 + half * 256 + k16 * 16) ^ ((r & 7) << 4);
        *(bf16x8*)(dst + byte) = v;
    }
    // TSt[c][PADR] stripe
    {
        int r = tid & 127, cg = tid >> 7;
        int p = p0 + r;
        bool act = p < TOTAL;
        for (int i2 = 0; i2 < 64; ++i2) {
            int cl = cg * 64 + i2;
            unsigned short v = 0;
            if (act) {
                float ht = fmaxf(zr[r][0] * wsg[0][cl] + zr[r][1] * wsg[1][cl] +
                                 zr[r][2] * wsg[2][cl] + wsg[3][cl], 0.f);
                v = (unsigned short)f2bs(tanhf(Et[r][cl] + ht));
            }
            TSt[(size_t)(half * 128 + cl) * PADR + p0 + r] = v;
        }
    }
}

// ---------------- K6c: bilinear, A-static-LDS + B-streamed pipelined MFMA --------
// Block 512 thr = 8 waves (wr2 x wc4), tile M=128 x N=256, K=256 per o, nO o's.
// A staged ONCE (64KB); B double-buffered, counted vmcnt(4), never drained.
// 2D XCD partition: xcd = (og/9)*2 + (mt>=14); per-XCD resident ~2MB < 4MB L2.
#define STAGE(C, BUF) do { \
    int c_ = (C); \
    int o_ = og + NOGv * (c_ >> 2); \
    int kc_ = c_ & 3; \
    const char* Bs_ = Wf + ((size_t)(o_ * 4 + kc_)) * 32768; \
    _Pragma("unroll") \
    for (int i_ = 0; i_ < 4; ++i_) \
        gload16(Bs_ + (i_ * 512 + tid) * 16, Bb[BUF] + (i_ * 512 + tid) * 16); \
} while (0)

__launch_bounds__(512, 2)
__global__ void k_bil(const char* __restrict__ HSf, const unsigned short* __restrict__ TSt,
                      const char* __restrict__ Wf, const float* __restrict__ bbil,
                      float* __restrict__ out) {
    int f = blockIdx.x;
    int x = f & 7, sub = f >> 3;              // sub 0..125
    int q = x >> 1, h = x & 1;                // og-quarter, mt-half
    int og = q * 9 + sub / 14;                // 0..35
    int mt = h * 14 + sub % 14;               // 0..27
    int p0 = mt * MTv;
    int nO = (og < 25) ? 3 : 2;               // 25*3 + 11*2 = 97

    int tid = threadIdx.x;
    int lane = tid & 63, w = tid >> 6;
    int wr = w >> 2, wc = w & 3;              // wr 0..1, wc 0..3
    int lr = lane & 15, lg = lane >> 4;

    __shared__ char A_l[65536];
    __shared__ char Bb[2][32768];
    __shared__ float red[MTv][4];

    // TS fragments in registers: o-independent, loaded ONCE (32 VGPR)
    u32x2 tsv[4][4];
#pragma unroll
    for (int mi = 0; mi < 4; ++mi)
#pragma unroll
        for (int ni = 0; ni < 4; ++ni)
            tsv[mi][ni] = *(const u32x2*)(TSt + (size_t)(wc * 64 + ni * 16 + lr) * PADR +
                                          p0 + wr * 64 + mi * 16 + lg * 4);

    // prologue: A tile (once), then B chunks 0 and 1
    {
        const char* As = HSf + (size_t)mt * 65536;
#pragma unroll
        for (int i = 0; i < 8; ++i)
            gload16(As + (i * 512 + tid) * 16, A_l + (i * 512 + tid) * 16);
    }
    STAGE(0, 0);
    STAGE(1, 1);

    f32x4 acc[4][4];
#pragma unroll
    for (int mi = 0; mi < 4; ++mi)
#pragma unroll
        for (int ni = 0; ni < 4; ++ni) acc[mi][ni] = (f32x4){0.f, 0.f, 0.f, 0.f};

    int T = 4 * nO;
    for (int t = 0; t < T; ++t) {
        int cur = t & 1;
        int kc = t & 3;
        __builtin_amdgcn_sched_barrier(0);
        asm volatile("s_waitcnt vmcnt(4)" ::: "memory");   // TS+A+B_t landed; B_{t+1} in flight
        __builtin_amdgcn_sched_barrier(0);
        __builtin_amdgcn_s_barrier();
        __builtin_amdgcn_sched_barrier(0);

        const char* Bc = Bb[cur];
        int kA = kc * 128 + lg * 16;          // byte k-offset, half 0
        int kB = kA + 64;                     // half 1

        bf16x8 a0[4], b0[4];
#pragma unroll
        for (int mi = 0; mi < 4; ++mi) {
            int r = wr * 64 + mi * 16 + lr;
            a0[mi] = *(const bf16x8*)(A_l + ((r * 512 + kA) ^ ((r & 7) << 4)));
        }
#pragma unroll
        for (int ni = 0; ni < 4; ++ni) {
            int c = wc * 64 + ni * 16 + lr;
            b0[ni] = *(const bf16x8*)(Bc + ((c * 128 + lg * 16) ^ ((c & 7) << 4)));
        }
        __builtin_amdgcn_sched_barrier(0);
        asm volatile("s_waitcnt lgkmcnt(0)" ::: "memory");
        __builtin_amdgcn_sched_barrier(0);
        __builtin_amdgcn_s_setprio(1);
#pragma unroll
        for (int mi = 0; mi < 4; ++mi)
#pragma unroll
            for (int ni = 0; ni < 4; ++ni)
                acc[mi][ni] = __builtin_amdgcn_mfma_f32_16x16x32_bf16(a0[mi], b0[ni], acc[mi][ni], 0, 0, 0);
        __builtin_amdgcn_s_setprio(0);

        bf16x8 a1[4], b1[4];
#pragma unroll
        for (int mi = 0; mi < 4; ++mi) {
            int r = wr * 64 + mi * 16 + lr;
            a1[mi] = *(const bf16x8*)(A_l + ((r * 512 + kB) ^ ((r & 7) << 4)));
        }
#pragma unroll
        for (int ni = 0; ni < 4; ++ni) {
            int c = wc * 64 + ni * 16 + lr;
            b1[ni] = *(const bf16x8*)(Bc + ((c * 128 + 64 + lg * 16) ^ ((c & 7) << 4)));
        }
        __builtin_amdgcn_sched_barrier(0);
        asm volatile("s_waitcnt lgkmcnt(0)" ::: "memory");  // our reads of Bb[cur] retired
        __builtin_amdgcn_sched_barrier(0);
        __builtin_amdgcn_s_barrier();                       // every wave done reading Bb[cur]
        __builtin_amdgcn_sched_barrier(0);

        int tt = (t + 2 < T) ? t + 2 : T - 1;               // clamp keeps vmcnt uniform
        STAGE(tt, cur);
        __builtin_amdgcn_sched_barrier(0);
        __builtin_amdgcn_s_setprio(1);
#pragma unroll
        for (int mi = 0; mi < 4; ++mi)
#pragma unroll
            for (int ni = 0; ni < 4; ++ni)
                acc[mi][ni] = __builtin_amdgcn_mfma_f32_16x16x32_bf16(a1[mi], b1[ni], acc[mi][ni], 0, 0, 0);
        __builtin_amdgcn_s_setprio(0);

        if ((t & 3) == 3) {
            int o = og + NOGv * (t >> 2);
            // epilogue: dot with TS (registers), reduce over lr lanes
#pragma unroll
            for (int mi = 0; mi < 4; ++mi) {
                float s0 = 0.f, s1 = 0.f, s2 = 0.f, s3 = 0.f;
#pragma unroll
                for (int ni = 0; ni < 4; ++ni) {
                    unsigned lo = tsv[mi][ni][0], hi = tsv[mi][ni][1];
                    s0 += acc[mi][ni][0] * __uint_as_float(lo << 16);
                    s1 += acc[mi][ni][1] * __uint_as_float(lo & 0xFFFF0000u);
                    s2 += acc[mi][ni][2] * __uint_as_float(hi << 16);
                    s3 += acc[mi][ni][3] * __uint_as_float(hi & 0xFFFF0000u);
                    acc[mi][ni] = (f32x4){0.f, 0.f, 0.f, 0.f};
                }
#pragma unroll
                for (int off = 1; off < 16; off <<= 1) {
                    s0 += __shfl_xor(s0, off);
                    s1 += __shfl_xor(s1, off);
                    s2 += __shfl_xor(s2, off);
                    s3 += __shfl_xor(s3, off);
                }
                if (lr == 0) {
                    int rb = wr * 64 + mi * 16 + lg * 4;
                    red[rb + 0][wc] = s0;
                    red[rb + 1][wc] = s1;
                    red[rb + 2][wc] = s2;
                    red[rb + 3][wc] = s3;
                }
            }
            __builtin_amdgcn_sched_barrier(0);
            asm volatile("s_waitcnt lgkmcnt(0)" ::: "memory");
            __builtin_amdgcn_sched_barrier(0);
            __builtin_amdgcn_s_barrier();
            __builtin_amdgcn_sched_barrier(0);
            if (tid < MTv) {
                int p = p0 + tid;
                if (p < TOTAL)
                    out[(size_t)p * CC + o] =
                        red[tid][0] + red[tid][1] + red[tid][2] + red[tid][3] + bbil[o];
            }
        }
    }
}
#undef STAGE

extern "C" void kernel_launch(void* const* d_in, const int* in_sizes, int n_in,
                              void* d_out, int out_size, void* d_ws, size_t ws_size,
                              hipStream_t stream) {
    const float* seq   = (const float*)d_in[0];
    const float* att   = (const float*)d_in[1];
    const int*   midx  = (const int*)d_in[2];
    const int*   mmask = (const int*)d_in[3];
    const int*   hts   = (const int*)d_in[4];
    const float* Wlin  = (const float*)d_in[5];
    const float* blin  = (const float*)d_in[6];
    const float* Wseg  = (const float*)d_in[7];
    const float* bseg  = (const float*)d_in[8];
    const float* Whead = (const float*)d_in[9];
    const float* bhead = (const float*)d_in[10];
    const float* Wtail = (const float*)d_in[11];
    const float* btail = (const float*)d_in[12];
    const float* Wbil  = (const float*)d_in[13];
    const float* bbil  = (const float*)d_in[14];
    float* out = (float*)d_out;

    float* ws = (float*)d_ws;
    float* ent_emb = ws;                                     // 64512 f
    float* ea      = ent_emb + BB * NEz * DD;                // 1032192 f
    float* szp     = ea + (size_t)BB * NEz * HH * LL;        // 1806336 f
    float* zz      = szp + (size_t)BB * PAIRS * 128 * 4;     // 14112 f
    float* EWh     = zz + (size_t)BB * PAIRS * 4;            // 21504 f
    float* EWt     = EWh + BB * NEz * FF;                    // 21504 f
    char* Wf       = (char*)(EWt + BB * NEz * FF);           // 97*4*32768 B
    char* HSf      = Wf + (size_t)CC * 4 * 32768;            // 28*65536 B
    unsigned short* TSt = (unsigned short*)(HSf + (size_t)NTt * 65536);  // 256*3584

    k_ent_emb<<<BB * NEz, 256, 0, stream>>>(seq, midx, mmask, ent_emb);
    k_ent_att<<<BB * NEz * HH, 256, 0, stream>>>(att, midx, mmask, ea);
    k_pairAB<<<dim3(128, BB), 384, 0, stream>>>(ea, seq, Wlin, szp);
    k_zz<<<(BB * PAIRS * 8 + 255) / 256, 256, 0, stream>>>(szp, blin, zz);
    k_ew<<<BB * NEz, 256, 0, stream>>>(ent_emb, Whead, bhead, Wtail, btail, EWh, EWt);
    k_wt<<<CC * 4, 256, 0, stream>>>(Wbil, Wf);
    k_prep<<<NTt * 2, 256, 0, stream>>>(EWh, EWt, zz, Wseg, bseg, hts, HSf, TSt);
    k_bil<<<NWGv, 512, 0, stream>>>(HSf, TSt, Wf, bbil, out);
}